// Round 5
// baseline (100.998 us; speedup 1.0000x reference)
//
#include <hip/hip_runtime.h>
#include <math.h>

// InputMPNN on MI355X — MFMA formulation v3 (resubmit; R4 was an infra timeout).
// fmp: block = (b, 4 a's), 256 thr. F K-quarter per wave in REGISTERS (no LDS
//      B-reads -> kills the 8-way-conflict LDS wall of v2). Q double-buffered
//      16KB LDS per a; kb-contraction in-register + shfl + small LDS reduce.
// MLP: two 2048x256x256 bf16 MFMA GEMMs (unchanged, verified).
// bf16 operands PRE-SWIZZLED: elem k -> k ^ ((row&7)<<3)  (byte ^ ((row&7)<<4)).

typedef __attribute__((ext_vector_type(8))) short bf16x8;
typedef __attribute__((ext_vector_type(4))) float f32x4;
typedef unsigned short u16;

#define BB 8
#define NN 256
#define CC 128

__device__ __forceinline__ u16 f2bf(float f) {
    union { float f; unsigned int u; } v; v.f = f;
    unsigned int u = v.u;
    return (u16)((u + 0x7FFFu + ((u >> 16) & 1u)) >> 16);   // RNE
}

__device__ __forceinline__ void gld16(const void* g, void* l) {
    __builtin_amdgcn_global_load_lds(
        (const __attribute__((address_space(1))) void*)g,
        (__attribute__((address_space(3))) void*)l, 16, 0, 0);
}

#define MFMA(a, b, c) __builtin_amdgcn_mfma_f32_16x16x32_bf16((a), (b), (c), 0, 0, 0)

// ---------------- prep: transposes + bf16 converts (all pre-swizzled) -------
__global__ __launch_bounds__(256) void prep_kernel(
    const float* __restrict__ features, const float* __restrict__ W1,
    const float* __restrict__ W2, u16* __restrict__ Ft, u16* __restrict__ Xbf,
    u16* __restrict__ W1t, u16* __restrict__ W2t)
{
    __shared__ float S[64][65];
    const int blk = blockIdx.x, t = threadIdx.x;
    if (blk < 64) {                    // Ft[b][c][x^] = features[b][x][c]
        const int b = blk >> 3, tl = blk & 7, c0 = (tl >> 2) * 64, x0 = (tl & 3) * 64;
        const int j = t & 63, ri = t >> 6;
#pragma unroll
        for (int rr = 0; rr < 16; ++rr) {
            int xl = rr * 4 + ri;
            S[j][xl] = features[(size_t)(b * NN + x0 + xl) * CC + c0 + j];
        }
        __syncthreads();
#pragma unroll
        for (int rr = 0; rr < 16; ++rr) {
            int cl = rr * 4 + ri;
            int c = c0 + cl, x = x0 + j;
            Ft[(size_t)(b * CC + c) * NN + (x ^ ((c & 7) << 3))] = f2bf(S[cl][j]);
        }
    } else if (blk < 96) {             // W1t/W2t[n][k^] = W[k][n]
        const int isW2 = (blk >= 80), tl = (blk - 64) & 15;
        const int n0 = (tl >> 2) * 64, k0 = (tl & 3) * 64;
        const float* W = isW2 ? W2 : W1;
        u16* Wt = isW2 ? W2t : W1t;
        const int j = t & 63, ri = t >> 6;
#pragma unroll
        for (int rr = 0; rr < 16; ++rr) {
            int kl = rr * 4 + ri;
            S[j][kl] = W[(size_t)(k0 + kl) * 256 + n0 + j];
        }
        __syncthreads();
#pragma unroll
        for (int rr = 0; rr < 16; ++rr) {
            int nl = rr * 4 + ri;
            int n = n0 + nl, k = k0 + j;
            Wt[(size_t)n * 256 + (k ^ ((n & 7) << 3))] = f2bf(S[nl][j]);
        }
    } else {                           // Xbf feature half: col k = 128+c
        const int bi = blk - 96;       // 128 blocks x 16 rows
        const int r0 = bi * 16, c = t & 127, rs = t >> 7;
#pragma unroll
        for (int rr = 0; rr < 8; ++rr) {
            int row = r0 + rr * 2 + rs;
            float v = features[(size_t)row * CC + c];
            Xbf[(size_t)row * 256 + ((128 + c) ^ ((row & 7) << 3))] = f2bf(v);
        }
    }
}

// ---------------- fmp v3: F-in-registers, Q-only LDS ------------------------
#define WPS 129

__global__ __launch_bounds__(256, 2) void fmp_kernel(
    const float* __restrict__ norms, const u16* __restrict__ Ft,
    const float* __restrict__ rad_W, const float* __restrict__ rad_b,
    u16* __restrict__ Xbf)
{
    __shared__ __align__(16) char Qb[2][16384];      // 32 rows x 512 B each
    __shared__ float Wp[29 * WPS];
    __shared__ float Pst[4][128];

    // XCD-chunked swizzle: all blocks on XCD k share b = k -> Ft[b] L2-hot
    const int bid = blockIdx.x;
    const int swz = (bid & 7) * 64 + (bid >> 3);
    const int b = swz >> 6, a0 = (swz & 63) * 4;

    const int t = threadIdx.x, w = t >> 6, lane = t & 63;
    const int g = lane >> 4, rA = lane & 15;

    // ---- W' stage (29 x 128 f32) ----
    for (int idx = t; idx < 29 * 128; idx += 256) {
        int kb = idx >> 7, c = idx & 127;
        Wp[kb * WPS + c] = (kb < 28) ? rad_W[(size_t)(kb + 4) * CC + c] : rad_b[c];
    }
    // zero Q rows 29..31 (both buffers) once — never written by builds
#pragma unroll
    for (int i = 0; i < 3; ++i) {
        int idx = t + i * 256;                       // 768 u32 = 2 bufs x 3 rows
        int buf = idx >= 384, r = idx & 383;
        *(unsigned int*)(Qb[buf] + 29 * 512 + r * 4) = 0u;
    }

    // ---- F K-quarter into registers: wave w owns x in [64w, 64w+64) ----
    bf16x8 Freg[2][8];
    {
        const u16* fb = Ft + (size_t)b * 32768;
#pragma unroll
        for (int kq = 0; kq < 2; ++kq)
#pragma unroll
            for (int n = 0; n < 8; ++n) {
                int c = 16 * n + rA;
                int xb = 64 * w + 32 * kq + 8 * g;
                Freg[kq][n] = *(const bf16x8*)(fb + (size_t)c * 256 + (xb ^ ((c & 7) << 3)));
            }
    }

    // ---- main loop over the block's 4 a's, Q double-buffered ----
#pragma unroll 1
    for (int ia = -1; ia < 4; ++ia) {
        if (ia >= 0) {
            __syncthreads();                          // Q[ia&1] ready, Pst free
            char* q = Qb[ia & 1];
            // MFMA phase: 4 LDS A-reads, 32 MFMA
            f32x4 acc[2][8] = {};
#pragma unroll
            for (int kq = 0; kq < 2; ++kq) {
                const int inner = (128 * w + 64 * kq + 16 * g) ^ ((rA & 7) << 4);
                bf16x8 A0 = *(const bf16x8*)(q + (rA) * 512 + inner);
                bf16x8 A1 = *(const bf16x8*)(q + (16 + rA) * 512 + inner);
#pragma unroll
                for (int n = 0; n < 8; ++n) {
                    acc[0][n] = MFMA(A0, Freg[kq][n], acc[0][n]);
                    acc[1][n] = MFMA(A1, Freg[kq][n], acc[1][n]);
                }
            }
            // build next-a Q into other buffer (overlaps epilogue latency)
            if (ia < 3) {
                char* qn = Qb[(ia + 1) & 1];
                const float r_ = norms[((size_t)(b * NN + a0 + ia + 1)) * NN + t];
                const float ir = 1.0f / r_;
                float s1, c1v;
                __sincosf(6.28318530717958647692f * r_, &s1, &c1v);
                const float s2 = 2.0f * s1 * c1v, c2 = c1v * c1v - s1 * s1;
                const float s3 = s1 * c2 + c1v * s2, c3 = c1v * c2 - s1 * s2;
                float cut = 0.0f;
                if (r_ < 1.73f) cut = 1.0f / (1.0f + __expf((r_ - 1.73f) * 5.0f));
                const float tv[7] = { s1, s2, s3, 1.0f, c1v, c2, c3 };
                const float po[4] = { cut, cut * ir, cut * ir * ir, cut * ir * ir * ir };
#pragma unroll
                for (int i = 0; i < 7; ++i)
#pragma unroll
                    for (int pw = 0; pw < 4; ++pw) {
                        int kb = i * 4 + pw;
                        *(u16*)(qn + kb * 512 + ((2 * t) ^ ((kb & 7) << 4))) =
                            f2bf(tv[i] * po[pw]);
                    }
                *(u16*)(qn + 28 * 512 + ((2 * t) ^ ((28 & 7) << 4))) = f2bf(cut);
            }
            // kb-contraction (in-register) + g-reduce
            float P[8] = {};
#pragma unroll
            for (int m = 0; m < 2; ++m)
#pragma unroll
                for (int r = 0; r < 4; ++r) {
                    const int kb = 16 * m + 4 * g + r;
                    if (kb < 29) {
#pragma unroll
                        for (int n = 0; n < 8; ++n)
                            P[n] = fmaf(Wp[kb * WPS + 16 * n + rA], acc[m][n][r], P[n]);
                    }
                }
#pragma unroll
            for (int n = 0; n < 8; ++n) {
                P[n] += __shfl_xor(P[n], 16);
                P[n] += __shfl_xor(P[n], 32);
            }
            if (g == 0)
#pragma unroll
                for (int n = 0; n < 8; ++n) Pst[w][16 * n + rA] = P[n];
            __syncthreads();                          // Pst complete
            if (t < 128) {
                const int row = b * NN + a0 + ia;
                float s = Pst[0][t] + Pst[1][t] + Pst[2][t] + Pst[3][t];
                Xbf[(size_t)row * 256 + (t ^ ((row & 7) << 3))] = f2bf(s);
            }
        } else {
            // prologue: build Q[0] for a0
            char* qn = Qb[0];
            const float r_ = norms[((size_t)(b * NN + a0)) * NN + t];
            const float ir = 1.0f / r_;
            float s1, c1v;
            __sincosf(6.28318530717958647692f * r_, &s1, &c1v);
            const float s2 = 2.0f * s1 * c1v, c2 = c1v * c1v - s1 * s1;
            const float s3 = s1 * c2 + c1v * s2, c3 = c1v * c2 - s1 * s2;
            float cut = 0.0f;
            if (r_ < 1.73f) cut = 1.0f / (1.0f + __expf((r_ - 1.73f) * 5.0f));
            const float tv[7] = { s1, s2, s3, 1.0f, c1v, c2, c3 };
            const float po[4] = { cut, cut * ir, cut * ir * ir, cut * ir * ir * ir };
#pragma unroll
            for (int i = 0; i < 7; ++i)
#pragma unroll
                for (int pw = 0; pw < 4; ++pw) {
                    int kb = i * 4 + pw;
                    *(u16*)(qn + kb * 512 + ((2 * t) ^ ((kb & 7) << 4))) =
                        f2bf(tv[i] * po[pw]);
                }
            *(u16*)(qn + 28 * 512 + ((2 * t) ^ ((28 & 7) << 4))) = f2bf(cut);
        }
    }
}

// ---------------- MLP: 2048x256x256 bf16 GEMM, 32x64 tiles ------------------
template <int LAYER>
__global__ __launch_bounds__(256) void mlp_kernel(
    const u16* __restrict__ X, const u16* __restrict__ Wt,
    const float* __restrict__ bias, void* __restrict__ outp)
{
    __shared__ __align__(16) char lds[48 * 1024];  // Xs 16KB | Ws 32KB
    const int r0 = blockIdx.x * 32, n0 = blockIdx.y * 64;
    const int t = threadIdx.x, w = t >> 6, lane = t & 63;
    const int g = lane >> 4, rA = lane & 15;

    const char* xs = (const char*)(X + (size_t)r0 * 256);
#pragma unroll
    for (int it = 0; it < 4; ++it)
        gld16(xs + it * 4096 + t * 16, lds + it * 4096 + w * 1024);
    const char* wsrc = (const char*)(Wt + (size_t)n0 * 256);
#pragma unroll
    for (int it = 0; it < 8; ++it)
        gld16(wsrc + it * 4096 + t * 16, lds + 16384 + it * 4096 + w * 1024);
    __syncthreads();

    const int mt = w & 1, np = w >> 1;
    const int sw = (rA & 7) << 4;
    const int aoff = (16 * mt + rA) * 512;
    const int boff = 16384 + (32 * np + rA) * 512;
    f32x4 acc[2] = {};
#pragma unroll
    for (int k0 = 0; k0 < 8; ++k0) {
        const int inner = (k0 * 64 + g * 16) ^ sw;
        bf16x8 a  = *(const bf16x8*)(lds + aoff + inner);
        bf16x8 b0 = *(const bf16x8*)(lds + boff + inner);
        bf16x8 b1 = *(const bf16x8*)(lds + boff + 16 * 512 + inner);
        acc[0] = MFMA(a, b0, acc[0]);
        acc[1] = MFMA(a, b1, acc[1]);
    }
#pragma unroll
    for (int i = 0; i < 2; ++i)
#pragma unroll
        for (int r = 0; r < 4; ++r) {
            int grow = r0 + 16 * mt + 4 * g + r;
            int gcol = n0 + 32 * np + 16 * i + rA;
            float v = acc[i][r] + bias[gcol];
            if (LAYER == 1) {
                v = (v > 0.0f) ? v : 0.01f * v;
                ((u16*)outp)[(size_t)grow * 256 + (gcol ^ ((grow & 7) << 3))] = f2bf(v);
            } else {
                ((float*)outp)[(size_t)grow * 256 + gcol] = v;
            }
        }
}

extern "C" void kernel_launch(void* const* d_in, const int* in_sizes, int n_in,
                              void* d_out, int out_size, void* d_ws, size_t ws_size,
                              hipStream_t stream) {
    const float* features = (const float*)d_in[0];
    const float* norms    = (const float*)d_in[4];
    const float* rad_W    = (const float*)d_in[5];
    const float* rad_b    = (const float*)d_in[6];
    const float* W1       = (const float*)d_in[7];
    const float* b1       = (const float*)d_in[8];
    const float* W2       = (const float*)d_in[9];
    const float* b2       = (const float*)d_in[10];

    char* ws = (char*)d_ws;
    u16* Ft  = (u16*)ws;                              // 512 KB
    u16* Xbf = (u16*)(ws + 524288);                   // 1 MB  [fmp | features] bf16
    u16* Hbf = (u16*)(ws + 524288 + 1048576);         // 1 MB
    u16* W1t = (u16*)(ws + 524288 + 2097152);         // 128 KB
    u16* W2t = (u16*)(ws + 524288 + 2097152 + 131072);// 128 KB

    prep_kernel<<<224, 256, 0, stream>>>(features, W1, W2, Ft, Xbf, W1t, W2t);
    fmp_kernel<<<512, 256, 0, stream>>>(norms, Ft, rad_W, rad_b, Xbf);
    mlp_kernel<1><<<dim3(64, 4), 256, 0, stream>>>(Xbf, W1t, b1, Hbf);
    mlp_kernel<2><<<dim3(64, 4), 256, 0, stream>>>(Hbf, W2t, b2, d_out);
}

// Round 6
// 93.270 us; speedup vs baseline: 1.0828x; 1.0828x over previous
//
#include <hip/hip_runtime.h>
#include <math.h>

// InputMPNN on MI355X — MFMA formulation v4.
// fmp: block = (b, 4 a's), 256 thr, ONE barrier. Wave w owns c in [32w,32w+32)
//      over full K=256 (c-split) -> kb-contraction is wave-local. F and W' in
//      REGISTERS (v3's per-a LDS W'-epilogue was the regression: ~6 us/CU of
//      ds_read_b32 + 2 barriers per a). Q tiles (4 x 16KB) built once in LDS.
// MLP: two 2048x256x256 bf16 MFMA GEMMs (unchanged, verified).
// bf16 operands PRE-SWIZZLED: elem k -> k ^ ((row&7)<<3)  (byte ^ ((row&7)<<4)).

typedef __attribute__((ext_vector_type(8))) short bf16x8;
typedef __attribute__((ext_vector_type(4))) float f32x4;
typedef unsigned short u16;

#define BB 8
#define NN 256
#define CC 128

__device__ __forceinline__ u16 f2bf(float f) {
    union { float f; unsigned int u; } v; v.f = f;
    unsigned int u = v.u;
    return (u16)((u + 0x7FFFu + ((u >> 16) & 1u)) >> 16);   // RNE
}

__device__ __forceinline__ void gld16(const void* g, void* l) {
    __builtin_amdgcn_global_load_lds(
        (const __attribute__((address_space(1))) void*)g,
        (__attribute__((address_space(3))) void*)l, 16, 0, 0);
}

#define MFMA(a, b, c) __builtin_amdgcn_mfma_f32_16x16x32_bf16((a), (b), (c), 0, 0, 0)

// ---------------- prep: transposes + bf16 converts (all pre-swizzled) -------
__global__ __launch_bounds__(256) void prep_kernel(
    const float* __restrict__ features, const float* __restrict__ W1,
    const float* __restrict__ W2, u16* __restrict__ Ft, u16* __restrict__ Xbf,
    u16* __restrict__ W1t, u16* __restrict__ W2t)
{
    __shared__ float S[64][65];
    const int blk = blockIdx.x, t = threadIdx.x;
    if (blk < 64) {                    // Ft[b][c][x^] = features[b][x][c]
        const int b = blk >> 3, tl = blk & 7, c0 = (tl >> 2) * 64, x0 = (tl & 3) * 64;
        const int j = t & 63, ri = t >> 6;
#pragma unroll
        for (int rr = 0; rr < 16; ++rr) {
            int xl = rr * 4 + ri;
            S[j][xl] = features[(size_t)(b * NN + x0 + xl) * CC + c0 + j];
        }
        __syncthreads();
#pragma unroll
        for (int rr = 0; rr < 16; ++rr) {
            int cl = rr * 4 + ri;
            int c = c0 + cl, x = x0 + j;
            Ft[(size_t)(b * CC + c) * NN + (x ^ ((c & 7) << 3))] = f2bf(S[cl][j]);
        }
    } else if (blk < 96) {             // W1t/W2t[n][k^] = W[k][n]
        const int isW2 = (blk >= 80), tl = (blk - 64) & 15;
        const int n0 = (tl >> 2) * 64, k0 = (tl & 3) * 64;
        const float* W = isW2 ? W2 : W1;
        u16* Wt = isW2 ? W2t : W1t;
        const int j = t & 63, ri = t >> 6;
#pragma unroll
        for (int rr = 0; rr < 16; ++rr) {
            int kl = rr * 4 + ri;
            S[j][kl] = W[(size_t)(k0 + kl) * 256 + n0 + j];
        }
        __syncthreads();
#pragma unroll
        for (int rr = 0; rr < 16; ++rr) {
            int nl = rr * 4 + ri;
            int n = n0 + nl, k = k0 + j;
            Wt[(size_t)n * 256 + (k ^ ((n & 7) << 3))] = f2bf(S[nl][j]);
        }
    } else {                           // Xbf feature half: col k = 128+c
        const int bi = blk - 96;       // 128 blocks x 16 rows
        const int r0 = bi * 16, c = t & 127, rs = t >> 7;
#pragma unroll
        for (int rr = 0; rr < 8; ++rr) {
            int row = r0 + rr * 2 + rs;
            float v = features[(size_t)row * CC + c];
            Xbf[(size_t)row * 256 + ((128 + c) ^ ((row & 7) << 3))] = f2bf(v);
        }
    }
}

// ---------------- fmp v4: c-split waves, reg-F, reg-W', one barrier ---------
__global__ __launch_bounds__(256, 2) void fmp_kernel(
    const float* __restrict__ norms, const u16* __restrict__ Ft,
    const float* __restrict__ rad_W, const float* __restrict__ rad_b,
    u16* __restrict__ Xbf)
{
    __shared__ __align__(16) char Q4[4][16384];     // [a][32 kb rows][512 B]

    // XCD-chunked swizzle: all blocks on XCD k share b=k -> Ft[b] L2-hot
    const int bid = blockIdx.x;
    const int swz = (bid & 7) * 64 + (bid >> 3);
    const int b = swz >> 6, a0 = (swz & 63) * 4;

    const int t = threadIdx.x, w = t >> 6, lane = t & 63;
    const int g = lane >> 4, rA = lane & 15;

    // ---- F into registers: wave w owns c in [32w,32w+32) over full K ----
    bf16x8 Freg[8][2];
    {
        const u16* fb = Ft + (size_t)b * 32768;
#pragma unroll
        for (int kq = 0; kq < 8; ++kq)
#pragma unroll
            for (int n = 0; n < 2; ++n) {
                int c = 32 * w + 16 * n + rA;
                int xb = 32 * kq + 8 * g;
                Freg[kq][n] = *(const bf16x8*)(fb + (size_t)c * 256 + (xb ^ ((c & 7) << 3)));
            }
    }

    // ---- W' into registers (16 values/thread, once per block) ----
    float Wreg[2][2][4];
#pragma unroll
    for (int m = 0; m < 2; ++m)
#pragma unroll
        for (int n = 0; n < 2; ++n)
#pragma unroll
            for (int r = 0; r < 4; ++r) {
                const int kb = 16 * m + 4 * g + r;
                const int c = 32 * w + 16 * n + rA;
                float v;
                if (kb < 28)       v = rad_W[(size_t)(kb + 4) * CC + c];
                else if (kb == 28) v = rad_b[c];
                else               v = 0.f;
                Wreg[m][n][r] = v;
            }

    // ---- zero Q rows 29..31 of all 4 tiles (uninit LDS may hold NaN) ----
#pragma unroll
    for (int i = 0; i < 6; ++i) {
        int idx = t + i * 256;                 // 1536 u32 = 4 tiles x 3 rows x 128
        int a = idx / 384, rm = idx - a * 384;
        *(unsigned int*)(Q4[a] + 29 * 512 + rm * 4) = 0u;
    }

    // ---- build all 4 Q tiles (thread t = neighbor x = t) ----
    float rv[4];
#pragma unroll
    for (int ia = 0; ia < 4; ++ia)
        rv[ia] = norms[((size_t)(b * NN + a0 + ia)) * NN + t];
#pragma unroll
    for (int ia = 0; ia < 4; ++ia) {
        const float r_ = rv[ia];
        const float ir = 1.0f / r_;
        float s1, c1v;
        __sincosf(6.28318530717958647692f * r_, &s1, &c1v);
        const float s2 = 2.0f * s1 * c1v, c2 = c1v * c1v - s1 * s1;
        const float s3 = s1 * c2 + c1v * s2, c3 = c1v * c2 - s1 * s2;
        float cut = 0.0f;
        if (r_ < 1.73f) cut = 1.0f / (1.0f + __expf((r_ - 1.73f) * 5.0f));
        const float tv[7] = { s1, s2, s3, 1.0f, c1v, c2, c3 };
        const float po[4] = { cut, cut * ir, cut * ir * ir, cut * ir * ir * ir };
        char* qn = Q4[ia];
#pragma unroll
        for (int i = 0; i < 7; ++i)
#pragma unroll
            for (int pw = 0; pw < 4; ++pw) {
                int kb = i * 4 + pw;
                *(u16*)(qn + kb * 512 + ((2 * t) ^ ((kb & 7) << 4))) =
                    f2bf(tv[i] * po[pw]);
            }
        *(u16*)(qn + 28 * 512 + ((2 * t) ^ ((28 & 7) << 4))) = f2bf(cut);
    }
    __syncthreads();                            // the ONLY barrier

    // ---- per-a: MFMA (32) + register epilogue ----
#pragma unroll 1
    for (int ia = 0; ia < 4; ++ia) {
        const char* q = Q4[ia];
        f32x4 acc[2][2] = {};
#pragma unroll
        for (int kq = 0; kq < 8; ++kq) {
            const int inner = (kq * 64 + g * 16) ^ ((rA & 7) << 4);
            bf16x8 A0 = *(const bf16x8*)(q + rA * 512 + inner);
            bf16x8 A1 = *(const bf16x8*)(q + (16 + rA) * 512 + inner);
            acc[0][0] = MFMA(A0, Freg[kq][0], acc[0][0]);
            acc[0][1] = MFMA(A0, Freg[kq][1], acc[0][1]);
            acc[1][0] = MFMA(A1, Freg[kq][0], acc[1][0]);
            acc[1][1] = MFMA(A1, Freg[kq][1], acc[1][1]);
        }
        float P0 = 0.f, P1 = 0.f;
#pragma unroll
        for (int m = 0; m < 2; ++m)
#pragma unroll
            for (int r = 0; r < 4; ++r) {
                P0 = fmaf(Wreg[m][0][r], acc[m][0][r], P0);
                P1 = fmaf(Wreg[m][1][r], acc[m][1][r], P1);
            }
        P0 += __shfl_xor(P0, 16); P0 += __shfl_xor(P0, 32);
        P1 += __shfl_xor(P1, 16); P1 += __shfl_xor(P1, 32);
        if (g == 0) {
            const int row = b * NN + a0 + ia;
            const int c0 = 32 * w + rA, c1 = c0 + 16;
            Xbf[(size_t)row * 256 + (c0 ^ ((row & 7) << 3))] = f2bf(P0);
            Xbf[(size_t)row * 256 + (c1 ^ ((row & 7) << 3))] = f2bf(P1);
        }
    }
}

// ---------------- MLP: 2048x256x256 bf16 GEMM, 32x64 tiles ------------------
template <int LAYER>
__global__ __launch_bounds__(256) void mlp_kernel(
    const u16* __restrict__ X, const u16* __restrict__ Wt,
    const float* __restrict__ bias, void* __restrict__ outp)
{
    __shared__ __align__(16) char lds[48 * 1024];  // Xs 16KB | Ws 32KB
    const int r0 = blockIdx.x * 32, n0 = blockIdx.y * 64;
    const int t = threadIdx.x, w = t >> 6, lane = t & 63;
    const int g = lane >> 4, rA = lane & 15;

    const char* xs = (const char*)(X + (size_t)r0 * 256);
#pragma unroll
    for (int it = 0; it < 4; ++it)
        gld16(xs + it * 4096 + t * 16, lds + it * 4096 + w * 1024);
    const char* wsrc = (const char*)(Wt + (size_t)n0 * 256);
#pragma unroll
    for (int it = 0; it < 8; ++it)
        gld16(wsrc + it * 4096 + t * 16, lds + 16384 + it * 4096 + w * 1024);
    __syncthreads();

    const int mt = w & 1, np = w >> 1;
    const int sw = (rA & 7) << 4;
    const int aoff = (16 * mt + rA) * 512;
    const int boff = 16384 + (32 * np + rA) * 512;
    f32x4 acc[2] = {};
#pragma unroll
    for (int k0 = 0; k0 < 8; ++k0) {
        const int inner = (k0 * 64 + g * 16) ^ sw;
        bf16x8 a  = *(const bf16x8*)(lds + aoff + inner);
        bf16x8 b0 = *(const bf16x8*)(lds + boff + inner);
        bf16x8 b1 = *(const bf16x8*)(lds + boff + 16 * 512 + inner);
        acc[0] = MFMA(a, b0, acc[0]);
        acc[1] = MFMA(a, b1, acc[1]);
    }
#pragma unroll
    for (int i = 0; i < 2; ++i)
#pragma unroll
        for (int r = 0; r < 4; ++r) {
            int grow = r0 + 16 * mt + 4 * g + r;
            int gcol = n0 + 32 * np + 16 * i + rA;
            float v = acc[i][r] + bias[gcol];
            if (LAYER == 1) {
                v = (v > 0.0f) ? v : 0.01f * v;
                ((u16*)outp)[(size_t)grow * 256 + (gcol ^ ((grow & 7) << 3))] = f2bf(v);
            } else {
                ((float*)outp)[(size_t)grow * 256 + gcol] = v;
            }
        }
}

extern "C" void kernel_launch(void* const* d_in, const int* in_sizes, int n_in,
                              void* d_out, int out_size, void* d_ws, size_t ws_size,
                              hipStream_t stream) {
    const float* features = (const float*)d_in[0];
    const float* norms    = (const float*)d_in[4];
    const float* rad_W    = (const float*)d_in[5];
    const float* rad_b    = (const float*)d_in[6];
    const float* W1       = (const float*)d_in[7];
    const float* b1       = (const float*)d_in[8];
    const float* W2       = (const float*)d_in[9];
    const float* b2       = (const float*)d_in[10];

    char* ws = (char*)d_ws;
    u16* Ft  = (u16*)ws;                              // 512 KB
    u16* Xbf = (u16*)(ws + 524288);                   // 1 MB  [fmp | features] bf16
    u16* Hbf = (u16*)(ws + 524288 + 1048576);         // 1 MB
    u16* W1t = (u16*)(ws + 524288 + 2097152);         // 128 KB
    u16* W2t = (u16*)(ws + 524288 + 2097152 + 131072);// 128 KB

    prep_kernel<<<224, 256, 0, stream>>>(features, W1, W2, Ft, Xbf, W1t, W2t);
    fmp_kernel<<<512, 256, 0, stream>>>(norms, Ft, rad_W, rad_b, Xbf);
    mlp_kernel<1><<<dim3(64, 4), 256, 0, stream>>>(Xbf, W1t, b1, Hbf);
    mlp_kernel<2><<<dim3(64, 4), 256, 0, stream>>>(Hbf, W2t, b2, d_out);
}

// Round 7
// 92.107 us; speedup vs baseline: 1.0965x; 1.0126x over previous
//
#include <hip/hip_runtime.h>
#include <math.h>

// InputMPNN on MI355X — v5: full row-local fusion.
// K1 prep: Ft[b][c][x^], W1t/W2t[n][k^] transposes (bf16, pre-swizzled).
// K2 fused: block = (b, 8 rows). Two 4-wave groups each run the v4 fmp
//   structure (F K-slices + W' in registers, Q tiles in LDS) -> X tile in LDS
//   (fmp half + features half) -> mlp1 (H in LDS) -> mlp2 -> out. W1t/W2t
//   B-frags read directly from global (L2-resident, shared by all blocks).
// bf16 operands PRE-SWIZZLED: elem k -> k ^ ((row&7)<<3) (byte ^ ((row&7)<<4)).

typedef __attribute__((ext_vector_type(8))) short bf16x8;
typedef __attribute__((ext_vector_type(4))) float f32x4;
typedef unsigned short u16;

#define BB 8
#define NN 256
#define CC 128

__device__ __forceinline__ u16 f2bf(float f) {
    union { float f; unsigned int u; } v; v.f = f;
    unsigned int u = v.u;
    return (u16)((u + 0x7FFFu + ((u >> 16) & 1u)) >> 16);   // RNE
}

#define MFMA(a, b, c) __builtin_amdgcn_mfma_f32_16x16x32_bf16((a), (b), (c), 0, 0, 0)

// ---------------- prep: transposes + bf16 converts (all pre-swizzled) -------
__global__ __launch_bounds__(256) void prep_kernel(
    const float* __restrict__ features, const float* __restrict__ W1,
    const float* __restrict__ W2, u16* __restrict__ Ft,
    u16* __restrict__ W1t, u16* __restrict__ W2t)
{
    __shared__ float S[64][65];
    const int blk = blockIdx.x, t = threadIdx.x;
    if (blk < 64) {                    // Ft[b][c][x^] = features[b][x][c]
        const int b = blk >> 3, tl = blk & 7, c0 = (tl >> 2) * 64, x0 = (tl & 3) * 64;
        const int j = t & 63, ri = t >> 6;
#pragma unroll
        for (int rr = 0; rr < 16; ++rr) {
            int xl = rr * 4 + ri;
            S[j][xl] = features[(size_t)(b * NN + x0 + xl) * CC + c0 + j];
        }
        __syncthreads();
#pragma unroll
        for (int rr = 0; rr < 16; ++rr) {
            int cl = rr * 4 + ri;
            int c = c0 + cl, x = x0 + j;
            Ft[(size_t)(b * CC + c) * NN + (x ^ ((c & 7) << 3))] = f2bf(S[cl][j]);
        }
    } else {                           // W1t/W2t[n][k^] = W[k][n]
        const int isW2 = (blk >= 80), tl = (blk - 64) & 15;
        const int n0 = (tl >> 2) * 64, k0 = (tl & 3) * 64;
        const float* W = isW2 ? W2 : W1;
        u16* Wt = isW2 ? W2t : W1t;
        const int j = t & 63, ri = t >> 6;
#pragma unroll
        for (int rr = 0; rr < 16; ++rr) {
            int kl = rr * 4 + ri;
            S[j][kl] = W[(size_t)(k0 + kl) * 256 + n0 + j];
        }
        __syncthreads();
#pragma unroll
        for (int rr = 0; rr < 16; ++rr) {
            int nl = rr * 4 + ri;
            int n = n0 + nl, k = k0 + j;
            Wt[(size_t)n * 256 + (k ^ ((n & 7) << 3))] = f2bf(S[nl][j]);
        }
    }
}

// ---------------- fused: fmp + MLP, row-local ------------------------------
__global__ __launch_bounds__(512, 1) void fused_kernel(
    const float* __restrict__ norms, const float* __restrict__ features,
    const u16* __restrict__ Ft,
    const float* __restrict__ rad_W, const float* __restrict__ rad_b,
    const u16* __restrict__ W1t, const float* __restrict__ b1,
    const u16* __restrict__ W2t, const float* __restrict__ b2,
    float* __restrict__ out)
{
    __shared__ __align__(16) char Q[8][16384];     // 128 KB: 8 a-tiles
    __shared__ __align__(16) u16 X[16][256];       // 8 KB (rows 8..15 pad)
    __shared__ __align__(16) u16 H[16][256];       // 8 KB

    // XCD swizzle: 32 consecutive blocks per XCD share b -> Ft[b] L2-hot
    const int bid = blockIdx.x;
    const int swz = (bid & 7) * 32 + (bid >> 3);
    const int b = swz >> 5, a0 = (swz & 31) * 8;

    const int t = threadIdx.x, w = t >> 6, lane = t & 63;
    const int g = lane >> 4, rA = lane & 15;
    const int wq = w & 3, grp = w >> 2;            // c-quarter, a-group

    // ---- F K-slices into registers (wave covers c in [32wq,32wq+32)) ----
    bf16x8 Freg[8][2];
    {
        const u16* fb = Ft + (size_t)b * 32768;
#pragma unroll
        for (int kq = 0; kq < 8; ++kq)
#pragma unroll
            for (int n = 0; n < 2; ++n) {
                int c = 32 * wq + 16 * n + rA;
                int xb = 32 * kq + 8 * g;
                Freg[kq][n] = *(const bf16x8*)(fb + (size_t)c * 256 + (xb ^ ((c & 7) << 3)));
            }
    }

    // ---- W' into registers ----
    float Wreg[2][2][4];
#pragma unroll
    for (int m = 0; m < 2; ++m)
#pragma unroll
        for (int n = 0; n < 2; ++n)
#pragma unroll
            for (int r = 0; r < 4; ++r) {
                const int kb = 16 * m + 4 * g + r;
                const int c = 32 * wq + 16 * n + rA;
                float v;
                if (kb < 28)       v = rad_W[(size_t)(kb + 4) * CC + c];
                else if (kb == 28) v = rad_b[c];
                else               v = 0.f;
                Wreg[m][n][r] = v;
            }

    // ---- zero Q rows 29..31 of all 8 tiles ----
#pragma unroll
    for (int i = 0; i < 6; ++i) {
        int idx = t + i * 512;                     // 3072 u32 = 8 x 3 x 128
        int tile = idx / 384, rm = idx - tile * 384;
        *(unsigned int*)(Q[tile] + 29 * 512 + rm * 4) = 0u;
    }

    // ---- build Q: thread handles x = t&255 for its group's 4 tiles ----
    {
        const int xq = t & 255, qg = t >> 8;
#pragma unroll
        for (int ia = 0; ia < 4; ++ia) {
            const float r_ = norms[((size_t)(b * NN + a0 + qg * 4 + ia)) * NN + xq];
            const float ir = 1.0f / r_;
            float s1, c1v;
            __sincosf(6.28318530717958647692f * r_, &s1, &c1v);
            const float s2 = 2.0f * s1 * c1v, c2 = c1v * c1v - s1 * s1;
            const float s3 = s1 * c2 + c1v * s2, c3 = c1v * c2 - s1 * s2;
            float cut = 0.0f;
            if (r_ < 1.73f) cut = 1.0f / (1.0f + __expf((r_ - 1.73f) * 5.0f));
            const float tv[7] = { s1, s2, s3, 1.0f, c1v, c2, c3 };
            const float po[4] = { cut, cut * ir, cut * ir * ir, cut * ir * ir * ir };
            char* qn = Q[qg * 4 + ia];
#pragma unroll
            for (int i = 0; i < 7; ++i)
#pragma unroll
                for (int pw = 0; pw < 4; ++pw) {
                    int kb = i * 4 + pw;
                    *(u16*)(qn + kb * 512 + ((2 * xq) ^ ((kb & 7) << 4))) =
                        f2bf(tv[i] * po[pw]);
                }
            *(u16*)(qn + 28 * 512 + ((2 * xq) ^ ((28 & 7) << 4))) = f2bf(cut);
        }
    }

    // ---- features -> X upper half (k = 128+c) ----
#pragma unroll
    for (int i = 0; i < 2; ++i) {
        int e = t + i * 512;                       // 1024 = 8 rows x 128 c
        int row = e >> 7, c = e & 127;
        float v = features[(size_t)(b * NN + a0 + row) * CC + c];
        X[row][(128 + c) ^ ((row & 7) << 3)] = f2bf(v);
    }
    __syncthreads();

    // ---- fmp MFMA + register epilogue -> X lower half ----
#pragma unroll 1
    for (int ia = 0; ia < 4; ++ia) {
        const char* q = Q[grp * 4 + ia];
        f32x4 acc[2][2] = {};
#pragma unroll
        for (int kq = 0; kq < 8; ++kq) {
            const int inner = (kq * 64 + g * 16) ^ ((rA & 7) << 4);
            bf16x8 A0 = *(const bf16x8*)(q + rA * 512 + inner);
            bf16x8 A1 = *(const bf16x8*)(q + (16 + rA) * 512 + inner);
            acc[0][0] = MFMA(A0, Freg[kq][0], acc[0][0]);
            acc[0][1] = MFMA(A0, Freg[kq][1], acc[0][1]);
            acc[1][0] = MFMA(A1, Freg[kq][0], acc[1][0]);
            acc[1][1] = MFMA(A1, Freg[kq][1], acc[1][1]);
        }
        float P0 = 0.f, P1 = 0.f;
#pragma unroll
        for (int m = 0; m < 2; ++m)
#pragma unroll
            for (int r = 0; r < 4; ++r) {
                P0 = fmaf(Wreg[m][0][r], acc[m][0][r], P0);
                P1 = fmaf(Wreg[m][1][r], acc[m][1][r], P1);
            }
        P0 += __shfl_xor(P0, 16); P0 += __shfl_xor(P0, 32);
        P1 += __shfl_xor(P1, 16); P1 += __shfl_xor(P1, 32);
        if (g == 0) {
            const int row = grp * 4 + ia;          // local row 0..7
            const int c0 = 32 * wq + rA, c1 = c0 + 16;
            X[row][c0 ^ ((row & 7) << 3)] = f2bf(P0);
            X[row][c1 ^ ((row & 7) << 3)] = f2bf(P1);
        }
    }
    __syncthreads();

    // ---- mlp1: A = X (LDS), B = W1t (global), H -> LDS ----
    {
        f32x4 acc[2] = {};
#pragma unroll
        for (int k0 = 0; k0 < 8; ++k0) {
            const int ke = (k0 * 32 + 8 * g);
            bf16x8 A = *(const bf16x8*)(&X[rA][ke ^ ((rA & 7) << 3)]);
#pragma unroll
            for (int nt = 0; nt < 2; ++nt) {
                const int col = 32 * w + 16 * nt + rA;
                bf16x8 Bv = *(const bf16x8*)(W1t + (size_t)col * 256 + (ke ^ ((col & 7) << 3)));
                acc[nt] = MFMA(A, Bv, acc[nt]);
            }
        }
#pragma unroll
        for (int nt = 0; nt < 2; ++nt)
#pragma unroll
            for (int r = 0; r < 4; ++r) {
                const int row = 4 * g + r;         // 0..15 (rows 8..15 pad)
                const int col = 32 * w + 16 * nt + rA;
                float v = acc[nt][r] + b1[col];
                v = (v > 0.f) ? v : 0.01f * v;
                H[row][col ^ ((row & 7) << 3)] = f2bf(v);
            }
    }
    __syncthreads();

    // ---- mlp2: A = H (LDS), B = W2t (global), store out ----
    {
        f32x4 acc[2] = {};
#pragma unroll
        for (int k0 = 0; k0 < 8; ++k0) {
            const int ke = (k0 * 32 + 8 * g);
            bf16x8 A = *(const bf16x8*)(&H[rA][ke ^ ((rA & 7) << 3)]);
#pragma unroll
            for (int nt = 0; nt < 2; ++nt) {
                const int col = 32 * w + 16 * nt + rA;
                bf16x8 Bv = *(const bf16x8*)(W2t + (size_t)col * 256 + (ke ^ ((col & 7) << 3)));
                acc[nt] = MFMA(A, Bv, acc[nt]);
            }
        }
#pragma unroll
        for (int nt = 0; nt < 2; ++nt)
#pragma unroll
            for (int r = 0; r < 4; ++r) {
                const int row = 4 * g + r;
                if (row < 8) {
                    const int col = 32 * w + 16 * nt + rA;
                    out[(size_t)(b * NN + a0 + row) * 256 + col] = acc[nt][r] + b2[col];
                }
            }
    }
}

extern "C" void kernel_launch(void* const* d_in, const int* in_sizes, int n_in,
                              void* d_out, int out_size, void* d_ws, size_t ws_size,
                              hipStream_t stream) {
    const float* features = (const float*)d_in[0];
    const float* norms    = (const float*)d_in[4];
    const float* rad_W    = (const float*)d_in[5];
    const float* rad_b    = (const float*)d_in[6];
    const float* W1       = (const float*)d_in[7];
    const float* b1       = (const float*)d_in[8];
    const float* W2       = (const float*)d_in[9];
    const float* b2       = (const float*)d_in[10];

    char* ws = (char*)d_ws;
    u16* Ft  = (u16*)ws;                  // 512 KB
    u16* W1t = (u16*)(ws + 524288);       // 128 KB
    u16* W2t = (u16*)(ws + 524288 + 131072);

    prep_kernel<<<96, 256, 0, stream>>>(features, W1, W2, Ft, W1t, W2t);
    fused_kernel<<<256, 512, 0, stream>>>(norms, features, Ft, rad_W, rad_b,
                                          W1t, b1, W2t, b2, (float*)d_out);
}